// Round 12
// baseline (2016.262 us; speedup 1.0000x reference)
//
#include <hip/hip_runtime.h>
#include <hip/hip_bf16.h>

// TransformerNMT r11: r10 + 128x128 tiles for QKV/crossKV GEMMs (2.6x MFMA
// density per barrier, m92/m103 prior) + merged attention-weight transpose.
// B=8, S=T=512, D=512, H=8, hd=64, L=6, DFF=2048, V=32000, PAD=0

#define Dm 512
#define Hh 8
#define HD 64
#define Ll 6
#define DFFv 2048
#define Vv 32000
#define Bb 8
#define Ss 512
#define NTOK (Bb * Ss)   // 4096 rows
#define NROWC ((size_t)NTOK * Dm)   // 2,097,152

typedef __bf16 bf16x8 __attribute__((ext_vector_type(8)));
typedef __bf16 bf16x4 __attribute__((ext_vector_type(4)));
typedef float  f32x4  __attribute__((ext_vector_type(4)));

#define GLOAD16(gp, lp) __builtin_amdgcn_global_load_lds( \
    (const __attribute__((address_space(1))) unsigned int*)(const void*)(gp), \
    (__attribute__((address_space(3))) unsigned int*)(void*)(lp), 16, 0, 0)

// ---------------------------------------------------------------- embed + PE (bf16 out)
__global__ void embed_pe_k(const int* __restrict__ tok_s, const int* __restrict__ tok_t,
                           const float* __restrict__ emb_s, const float* __restrict__ emb_t,
                           __bf16* __restrict__ out_s, __bf16* __restrict__ out_t)
{
    int row = blockIdx.x;
    int s = row & 511;
    const int* tok = blockIdx.y ? tok_t : tok_s;
    const float* emb = blockIdx.y ? emb_t : emb_s;
    __bf16* ob = (blockIdx.y ? out_t : out_s) + (size_t)row * Dm;
    int t = tok[row];
    const float* e = emb + (size_t)t * Dm;
    for (int dd = threadIdx.x; dd < Dm; dd += blockDim.x) {
        int j = dd >> 1;
        float div = expf((float)(2 * j) * (-9.210340371976184f / 512.0f));
        float ang = (float)s * div;
        float pe = (dd & 1) ? cosf(ang) : sinf(ang);
        ob[dd] = (__bf16)(e[dd] * 22.627416997969522f + pe);   // sqrt(512)
    }
}

// ---------------------------------------------------------------- weight transpose+convert
__global__ __launch_bounds__(256) void wtr_k(const float* __restrict__ W,
                                             __bf16* __restrict__ Wt, int K, int N)
{
    __shared__ float t[32][33];
    size_t msz = (size_t)K * N;
    const float* Wm = W + (size_t)blockIdx.z * msz;
    __bf16* Wtm = Wt + (size_t)blockIdx.z * msz;
    int n0 = blockIdx.x * 32, k0 = blockIdx.y * 32;
    int r = threadIdx.x >> 3, c4 = (threadIdx.x & 7) * 4;
    float4 v = *reinterpret_cast<const float4*>(&Wm[(size_t)(k0 + r) * N + n0 + c4]);
    t[r][c4] = v.x; t[r][c4 + 1] = v.y; t[r][c4 + 2] = v.z; t[r][c4 + 3] = v.w;
    __syncthreads();
    int n = threadIdx.x >> 3, kq = (threadIdx.x & 7) * 4;
    bf16x4 o;
    o[0] = (__bf16)t[kq + 0][n]; o[1] = (__bf16)t[kq + 1][n];
    o[2] = (__bf16)t[kq + 2][n]; o[3] = (__bf16)t[kq + 3][n];
    *reinterpret_cast<bf16x4*>(&Wtm[(size_t)(n0 + n) * K + k0 + kq]) = o;
}

// Merged 512x512 attention-weight transpose: z in [0,72), group = z/24
__global__ __launch_bounds__(256) void wtr_attn_k(const float* __restrict__ W0,
                                                  const float* __restrict__ W1,
                                                  const float* __restrict__ W2,
                                                  __bf16* __restrict__ D0,
                                                  __bf16* __restrict__ D1,
                                                  __bf16* __restrict__ D2)
{
    __shared__ float t[32][33];
    int grp = blockIdx.z / 24, mi = blockIdx.z % 24;
    const float* Wm = (grp == 0 ? W0 : grp == 1 ? W1 : W2) + (size_t)mi * Dm * Dm;
    __bf16* Wtm = (grp == 0 ? D0 : grp == 1 ? D1 : D2) + (size_t)mi * Dm * Dm;
    int n0 = blockIdx.x * 32, k0 = blockIdx.y * 32;
    int r = threadIdx.x >> 3, c4 = (threadIdx.x & 7) * 4;
    float4 v = *reinterpret_cast<const float4*>(&Wm[(size_t)(k0 + r) * Dm + n0 + c4]);
    t[r][c4] = v.x; t[r][c4 + 1] = v.y; t[r][c4 + 2] = v.z; t[r][c4 + 3] = v.w;
    __syncthreads();
    int n = threadIdx.x >> 3, kq = (threadIdx.x & 7) * 4;
    bf16x4 o;
    o[0] = (__bf16)t[kq + 0][n]; o[1] = (__bf16)t[kq + 1][n];
    o[2] = (__bf16)t[kq + 2][n]; o[3] = (__bf16)t[kq + 3][n];
    *reinterpret_cast<bf16x4*>(&Wtm[(size_t)(n0 + n) * Dm + k0 + kq]) = o;
}

// ---------------------------------------------------------------- MFMA GEMM (4 waves, BK=64)
// r6-proven 2-slot dbuf, plain __syncthreads, XOR-swizzled LDS.
// MODE 1: bf16 out (+RELU); MODE 2: fused QKV (N=1536);
// MODE 4: merged 6-layer cross-KV (N=6144, weight row = li*2048+512+cw).
template<int BM, int BN, int RELU, int MODE>
__global__ __launch_bounds__(256) void gemm_mfma_k(const __bf16* __restrict__ A,
                                                   const __bf16* __restrict__ Wt,
                                                   const float* __restrict__ bias,
                                                   void* __restrict__ Cout,
                                                   __bf16* __restrict__ out_k,
                                                   __bf16* __restrict__ out_vT,
                                                   int M, int N, int K)
{
    constexpr int NF_M = BM / 32;
    constexpr int NF_N = BN / 32;
    __shared__ __bf16 As[2][BM * 64];
    __shared__ __bf16 Bs[2][BN * 64];
    const int tid = threadIdx.x;
    const int wave = tid >> 6, lane = tid & 63;
    const int wr = wave >> 1, wc = wave & 1;
    const int row0 = blockIdx.y * BM, col0 = blockIdx.x * BN;

    f32x4 acc[NF_M][NF_N] = {};
    const int fr = lane & 15;
    const int kg = lane >> 4;

    auto stage = [&](int buf, int k0) {
        #pragma unroll
        for (int cc = 0; cc < BM / 32; ++cc) {
            int g = cc * 256 + tid;
            int r = g >> 3, gs = (g & 7) ^ (r & 7);
            GLOAD16(A + (size_t)(row0 + r) * K + k0 + gs * 8, &As[buf][g * 8]);
        }
        #pragma unroll
        for (int cc = 0; cc < BN / 32; ++cc) {
            int g = cc * 256 + tid;
            int r = g >> 3, gs = (g & 7) ^ (r & 7);
            int c = col0 + r;
            size_t wrow;
            if constexpr (MODE == 4)
                wrow = (size_t)(c >> 10) * 2048 + 512 + (c & 1023);
            else
                wrow = (size_t)c;
            GLOAD16(Wt + wrow * K + k0 + gs * 8, &Bs[buf][g * 8]);
        }
    };

    stage(0, 0);
    __syncthreads();                     // drains vmcnt -> tile 0 ready

    const int nk = K >> 6;
    for (int kb = 0; kb < nk; ++kb) {
        int cur = kb & 1;
        if (kb + 1 < nk) stage(cur ^ 1, (kb + 1) * 64);   // prefetch in flight

        const char* Ab  = (const char*)As[cur];
        const char* Bbp = (const char*)Bs[cur];
        #pragma unroll
        for (int ks = 0; ks < 2; ++ks) {
            bf16x8 af[NF_M], bq[NF_N];
            #pragma unroll
            for (int m = 0; m < NF_M; ++m) {
                int ar = wr * (BM / 2) + m * 16 + fr;
                af[m] = *reinterpret_cast<const bf16x8*>(
                    Ab + ar * 128 + (((ks * 4 + kg) ^ (ar & 7)) << 4));
            }
            #pragma unroll
            for (int n = 0; n < NF_N; ++n) {
                int br = wc * (BN / 2) + n * 16 + fr;
                bq[n] = *reinterpret_cast<const bf16x8*>(
                    Bbp + br * 128 + (((ks * 4 + kg) ^ (br & 7)) << 4));
            }
            #pragma unroll
            for (int m = 0; m < NF_M; ++m)
                #pragma unroll
                for (int n = 0; n < NF_N; ++n)
                    acc[m][n] = __builtin_amdgcn_mfma_f32_16x16x32_bf16(
                        af[m], bq[n], acc[m][n], 0, 0, 0);
        }
        __syncthreads();                 // prefetch drained + reads done
    }

    #pragma unroll
    for (int m = 0; m < NF_M; ++m) {
        #pragma unroll
        for (int n = 0; n < NF_N; ++n) {
            int colg = col0 + wc * (BN / 2) + n * 16 + fr;
            float bv;
            if constexpr (MODE == 4)
                bv = bias[(colg >> 10) * 2048 + 512 + (colg & 1023)];
            else
                bv = bias[colg];
            #pragma unroll
            for (int j = 0; j < 4; ++j) {
                int row = row0 + wr * (BM / 2) + m * 16 + kg * 4 + j;
                float v = acc[m][n][j] + bv;
                if (RELU) v = fmaxf(v, 0.f);
                if constexpr (MODE == 1) {
                    ((__bf16*)Cout)[(size_t)row * N + colg] = (__bf16)v;
                } else if constexpr (MODE == 2) {
                    int seg = colg >> 9;          // uniform per block (512%BN==0 or BN<=512)
                    int c = colg & 511;
                    if (seg == 0) {
                        ((__bf16*)Cout)[(size_t)row * 512 + c] = (__bf16)v;
                    } else if (seg == 1) {
                        out_k[(size_t)row * 512 + c] = (__bf16)v;
                    } else {
                        int bi = row >> 9, sI = row & 511;
                        int hh = c >> 6, f = c & 63;
                        out_vT[(size_t)((bi * 8 + hh) * 64 + f) * 512 + sI] = (__bf16)v;
                    }
                } else {   // MODE 4: merged cross-KV, layers stacked in N
                    int li = colg >> 10;
                    int cw = colg & 1023;
                    if (cw < 512) {
                        out_k[li * NROWC + (size_t)row * 512 + cw] = (__bf16)v;
                    } else {
                        int hh = (cw - 512) >> 6, f = (cw - 512) & 63;
                        int bi = row >> 9, sI = row & 511;
                        out_vT[li * NROWC +
                               (size_t)((bi * 8 + hh) * 64 + f) * 512 + sI] = (__bf16)v;
                    }
                }
            }
        }
    }
}

// ---------------------------------------------------------------- 256^2 8-wave GEMM (vocab)
__global__ __launch_bounds__(512) void gemm256_k(const __bf16* __restrict__ A,
                                                 const __bf16* __restrict__ Wt,
                                                 const float* __restrict__ bias,
                                                 float* __restrict__ C,
                                                 int M, int N, int K)
{
    __shared__ __bf16 As[2][256 * 64];
    __shared__ __bf16 Bs[2][256 * 64];
    const int tid = threadIdx.x;
    const int wave = tid >> 6, lane = tid & 63;
    const int wr = wave >> 2, wc = wave & 3;     // 2 x 4
    const int row0 = blockIdx.x * 256, col0 = blockIdx.y * 256;

    f32x4 acc[8][4] = {};
    const int fr = lane & 15;
    const int kg = lane >> 4;

    auto stage = [&](int buf, int k0) {
        #pragma unroll
        for (int cc = 0; cc < 4; ++cc) {
            int g = cc * 512 + tid;              // 0..2047
            int r = g >> 3, gs = (g & 7) ^ (r & 7);
            GLOAD16(A + (size_t)(row0 + r) * K + k0 + gs * 8, &As[buf][g * 8]);
        }
        #pragma unroll
        for (int cc = 0; cc < 4; ++cc) {
            int g = cc * 512 + tid;
            int r = g >> 3, gs = (g & 7) ^ (r & 7);
            GLOAD16(Wt + (size_t)(col0 + r) * K + k0 + gs * 8, &Bs[buf][g * 8]);
        }
    };

    stage(0, 0);
    __syncthreads();

    const int nk = K >> 6;
    for (int kb = 0; kb < nk; ++kb) {
        int cur = kb & 1;
        if (kb + 1 < nk) stage(cur ^ 1, (kb + 1) * 64);

        const char* Ab  = (const char*)As[cur];
        const char* Bbp = (const char*)Bs[cur];
        #pragma unroll
        for (int ks = 0; ks < 2; ++ks) {
            bf16x8 af[8], bq[4];
            #pragma unroll
            for (int m = 0; m < 8; ++m) {
                int ar = wr * 128 + m * 16 + fr;
                af[m] = *reinterpret_cast<const bf16x8*>(
                    Ab + ar * 128 + (((ks * 4 + kg) ^ (ar & 7)) << 4));
            }
            #pragma unroll
            for (int n = 0; n < 4; ++n) {
                int br = wc * 64 + n * 16 + fr;
                bq[n] = *reinterpret_cast<const bf16x8*>(
                    Bbp + br * 128 + (((ks * 4 + kg) ^ (br & 7)) << 4));
            }
            #pragma unroll
            for (int m = 0; m < 8; ++m)
                #pragma unroll
                for (int n = 0; n < 4; ++n)
                    acc[m][n] = __builtin_amdgcn_mfma_f32_16x16x32_bf16(
                        af[m], bq[n], acc[m][n], 0, 0, 0);
        }
        __syncthreads();
    }

    #pragma unroll
    for (int m = 0; m < 8; ++m) {
        #pragma unroll
        for (int n = 0; n < 4; ++n) {
            int colg = col0 + wc * 64 + n * 16 + fr;
            float bv = bias[colg];
            #pragma unroll
            for (int j = 0; j < 4; ++j) {
                int row = row0 + wr * 128 + m * 16 + kg * 4 + j;
                C[(size_t)row * N + colg] = acc[m][n][j] + bv;
            }
        }
    }
}

// ---------------------------------------------------------------- MFMA flash attention
__global__ __launch_bounds__(256) void attn_mfma_k(const __bf16* __restrict__ Qb,
                                                   const __bf16* __restrict__ Kb,
                                                   const __bf16* __restrict__ VbT,
                                                   __bf16* __restrict__ Ob,
                                                   const int* __restrict__ key_tok,
                                                   int causal)
{
    __shared__ __bf16 Ks[2][128 * 64];
    __shared__ __bf16 Vs[2][64 * 128];
    __shared__ __bf16 Pl[4][16 * 128];

    const int tid = threadIdx.x;
    const int w = tid >> 6, lane = tid & 63;
    const int fr = lane & 15, kg = lane >> 4;
    const int q0 = blockIdx.x * 64;
    const int h = blockIdx.y, b = blockIdx.z;
    const int qrow = q0 + w * 16 + fr;
    const int swz = (fr & 7) << 4;

    bf16x8 qf[2];
    {
        const __bf16* qp = Qb + ((size_t)(b * 512 + qrow) * 512 + h * 64 + kg * 8);
        qf[0] = *reinterpret_cast<const bf16x8*>(qp);
        qf[1] = *reinterpret_cast<const bf16x8*>(qp + 32);
    }

    f32x4 po[4] = {};
    float m_run = -3.0e38f, l_run = 0.f;
    __bf16* pw = Pl[w];

    auto stage = [&](int buf, int kk0) {
        #pragma unroll
        for (int c = 0; c < 4; ++c) {
            int ch = c * 256 + tid;
            int r = ch >> 3, gsk = (ch & 7) ^ (r & 7);
            GLOAD16(Kb + ((size_t)(b * 512 + kk0 + r) * 512 + h * 64 + gsk * 8),
                    &Ks[buf][ch * 8]);
            int f = ch >> 4, gsv = (ch & 15) ^ (f & 7);
            GLOAD16(VbT + ((size_t)((b * 8 + h) * 64 + f) * 512 + kk0 + gsv * 8),
                    &Vs[buf][ch * 8]);
        }
    };

    const int kkend = causal ? ((q0 + 64 + 127) & ~127) : 512;
    stage(0, 0);
    __syncthreads();

    for (int kk0 = 0; kk0 < kkend; kk0 += 128) {
        int cur = (kk0 >> 7) & 1;
        if (kk0 + 128 < kkend) stage(cur ^ 1, kk0 + 128);

        unsigned long long vm0 = __ballot(key_tok[b * 512 + kk0 + lane] != 0);
        unsigned long long vm1 = __ballot(key_tok[b * 512 + kk0 + 64 + lane] != 0);

        f32x4 st[8];
        #pragma unroll
        for (int kt = 0; kt < 8; ++kt) {
            f32x4 s = {};
            #pragma unroll
            for (int ks = 0; ks < 2; ++ks) {
                int byte = ((kt * 16 + fr) * 128 + ks * 64 + kg * 16) ^ swz;
                bf16x8 kf = *reinterpret_cast<const bf16x8*>((const char*)Ks[cur] + byte);
                s = __builtin_amdgcn_mfma_f32_16x16x32_bf16(kf, qf[ks], s, 0, 0, 0);
            }
            st[kt] = s;
        }

        float sv[8][4];
        float mloc = -3.0e38f;
        #pragma unroll
        for (int kt = 0; kt < 8; ++kt) {
            unsigned long long vm = (kt < 4) ? vm0 : vm1;
            #pragma unroll
            for (int j = 0; j < 4; ++j) {
                int kl = kt * 16 + kg * 4 + j;
                float s = st[kt][j] * 0.125f;
                bool ok = (vm >> (kl & 63)) & 1ull;
                if (causal && (kk0 + kl > qrow)) ok = false;
                s = ok ? s : -1e9f;
                sv[kt][j] = s;
                mloc = fmaxf(mloc, s);
            }
        }
        mloc = fmaxf(mloc, __shfl_xor(mloc, 16));
        mloc = fmaxf(mloc, __shfl_xor(mloc, 32));
        float m_new = fmaxf(m_run, mloc);
        float scale = __expf(m_run - m_new);
        float ls = 0.f;
        #pragma unroll
        for (int kt = 0; kt < 8; ++kt)
            #pragma unroll
            for (int j = 0; j < 4; ++j) {
                float p = __expf(sv[kt][j] - m_new);
                sv[kt][j] = p;
                ls += p;
            }
        ls += __shfl_xor(ls, 16);
        ls += __shfl_xor(ls, 32);
        l_run = l_run * scale + ls;
        m_run = m_new;

        #pragma unroll
        for (int kt = 0; kt < 8; ++kt)
            #pragma unroll
            for (int c = 0; c < 2; ++c) {
                union { __bf16 hh[2]; unsigned u; } pk;
                pk.hh[0] = (__bf16)sv[kt][2 * c];
                pk.hh[1] = (__bf16)sv[kt][2 * c + 1];
                int byte = (fr * 256 + kt * 32 + kg * 8 + c * 4) ^ swz;
                *reinterpret_cast<unsigned*>((char*)pw + byte) = pk.u;
            }

        {
            int qb4 = kg * 4;
            float s0 = __shfl(scale, qb4 + 0), s1 = __shfl(scale, qb4 + 1);
            float s2 = __shfl(scale, qb4 + 2), s3 = __shfl(scale, qb4 + 3);
            #pragma unroll
            for (int nf = 0; nf < 4; ++nf) {
                po[nf][0] *= s0; po[nf][1] *= s1;
                po[nf][2] *= s2; po[nf][3] *= s3;
            }
        }

        #pragma unroll
        for (int ks2 = 0; ks2 < 4; ++ks2) {
            int pbyte = (fr * 256 + ks2 * 64 + kg * 16) ^ swz;
            bf16x8 pa = *reinterpret_cast<const bf16x8*>((const char*)pw + pbyte);
            #pragma unroll
            for (int nf = 0; nf < 4; ++nf) {
                int vbyte = ((nf * 16 + fr) * 256 + ks2 * 64 + kg * 16) ^ swz;
                bf16x8 vf = *reinterpret_cast<const bf16x8*>((const char*)Vs[cur] + vbyte);
                po[nf] = __builtin_amdgcn_mfma_f32_16x16x32_bf16(pa, vf, po[nf], 0, 0, 0);
            }
        }
        __syncthreads();
    }

    {
        int qb4 = kg * 4;
        float r0 = 1.0f / __shfl(l_run, qb4 + 0);
        float r1 = 1.0f / __shfl(l_run, qb4 + 1);
        float r2 = 1.0f / __shfl(l_run, qb4 + 2);
        float r3 = 1.0f / __shfl(l_run, qb4 + 3);
        #pragma unroll
        for (int nf = 0; nf < 4; ++nf) {
            size_t base = (size_t)(b * 512 + q0 + w * 16 + qb4) * 512 + h * 64 + nf * 16 + fr;
            Ob[base]           = (__bf16)(po[nf][0] * r0);
            Ob[base + 512]     = (__bf16)(po[nf][1] * r1);
            Ob[base + 1024]    = (__bf16)(po[nf][2] * r2);
            Ob[base + 1536]    = (__bf16)(po[nf][3] * r3);
        }
    }
}

// ---------------------------------------------------------------- residual + LN, bf16 stream
__global__ __launch_bounds__(256) void add_ln_b_k(__bf16* __restrict__ xb,
                                                  const __bf16* __restrict__ ab,
                                                  const float* __restrict__ g,
                                                  const float* __restrict__ bb)
{
    const int w = threadIdx.x >> 6, lane = threadIdx.x & 63;
    const int row = blockIdx.x * 4 + w;
    const size_t base = (size_t)row * Dm + lane * 8;
    bf16x8 xv = *reinterpret_cast<const bf16x8*>(&xb[base]);
    bf16x8 av = *reinterpret_cast<const bf16x8*>(&ab[base]);
    float v[8];
    float s = 0.f, s2 = 0.f;
    #pragma unroll
    for (int j = 0; j < 8; ++j) {
        v[j] = (float)xv[j] + (float)av[j];
        s += v[j];
        s2 += v[j] * v[j];
    }
    #pragma unroll
    for (int o = 1; o < 64; o <<= 1) {
        s  += __shfl_xor(s, o);
        s2 += __shfl_xor(s2, o);
    }
    float mean = s * (1.0f / 512.0f);
    float var  = s2 * (1.0f / 512.0f) - mean * mean;
    float rstd = rsqrtf(var + 1e-5f);
    float4 g0 = *reinterpret_cast<const float4*>(&g[lane * 8]);
    float4 g1 = *reinterpret_cast<const float4*>(&g[lane * 8 + 4]);
    float4 b0 = *reinterpret_cast<const float4*>(&bb[lane * 8]);
    float4 b1 = *reinterpret_cast<const float4*>(&bb[lane * 8 + 4]);
    float gv[8] = {g0.x, g0.y, g0.z, g0.w, g1.x, g1.y, g1.z, g1.w};
    float bv[8] = {b0.x, b0.y, b0.z, b0.w, b1.x, b1.y, b1.z, b1.w};
    bf16x8 yv;
    #pragma unroll
    for (int j = 0; j < 8; ++j)
        yv[j] = (__bf16)((v[j] - mean) * rstd * gv[j] + bv[j]);
    *reinterpret_cast<bf16x8*>(&xb[base]) = yv;
}

// ---------------------------------------------------------------- launch
extern "C" void kernel_launch(void* const* d_in, const int* in_sizes, int n_in,
                              void* d_out, int out_size, void* d_ws, size_t ws_size,
                              hipStream_t stream)
{
    const int*   src        = (const int*)  d_in[0];
    const int*   tgt        = (const int*)  d_in[1];
    const float* src_emb    = (const float*)d_in[2];
    const float* tgt_emb    = (const float*)d_in[3];
    const float* enc_attn_w = (const float*)d_in[4];
    const float* enc_attn_b = (const float*)d_in[5];
    const float* enc_ffn_w1 = (const float*)d_in[6];
    const float* enc_ffn_b1 = (const float*)d_in[7];
    const float* enc_ffn_w2 = (const float*)d_in[8];
    const float* enc_ffn_b2 = (const float*)d_in[9];
    const float* enc_ln_g   = (const float*)d_in[10];
    const float* enc_ln_b   = (const float*)d_in[11];
    const float* dec_self_w = (const float*)d_in[12];
    const float* dec_self_b = (const float*)d_in[13];
    const float* dec_cross_w= (const float*)d_in[14];
    const float* dec_cross_b= (const float*)d_in[15];
    const float* dec_ffn_w1 = (const float*)d_in[16];
    const float* dec_ffn_b1 = (const float*)d_in[17];
    const float* dec_ffn_w2 = (const float*)d_in[18];
    const float* dec_ffn_b2 = (const float*)d_in[19];
    const float* dec_ln_g   = (const float*)d_in[20];
    const float* dec_ln_b   = (const float*)d_in[21];
    const float* out_w      = (const float*)d_in[22];
    const float* out_b      = (const float*)d_in[23];

    const size_t NROW = NROWC;                    // 2,097,152
    const size_t NH1  = (size_t)NTOK * DFFv;      // 8,388,608

    __bf16* xeb  = (__bf16*)d_ws;         // bf16 encoder stream
    __bf16* xdb  = xeb + NROW;            // bf16 decoder stream
    __bf16* t0b  = xdb + NROW;            // bf16 sublayer output (pre-LN)
    __bf16* qbb  = t0b + NROW;
    __bf16* kbb  = qbb + NROW;
    __bf16* vbT  = kbb + NROW;            // [(b*8+h)*64+f][512]
    __bf16* ctxb = vbT + NROW;
    __bf16* h1b  = ctxb + NROW;           // [4096,2048] bf16
    __bf16* kbb6 = h1b + NH1;             // 6 layers cross-K
    __bf16* vbT6 = kbb6 + 6 * NROW;       // 6 layers cross-V (transposed)

    const size_t WSZ  = (size_t)Dm * Dm;          // 262144
    const size_t FSZ  = (size_t)Dm * DFFv;        // 1048576
    __bf16* w_enc_attn = vbT6 + 6 * NROW;
    __bf16* w_enc_f1   = w_enc_attn + 24 * WSZ;
    __bf16* w_enc_f2   = w_enc_f1 + 6 * FSZ;
    __bf16* w_dec_self = w_enc_f2 + 6 * FSZ;
    __bf16* w_dec_cross= w_dec_self + 24 * WSZ;
    __bf16* w_dec_f1   = w_dec_cross + 24 * WSZ;
    __bf16* w_dec_f2   = w_dec_f1 + 6 * FSZ;
    __bf16* w_out      = w_dec_f2 + 6 * FSZ;      // 512*32000

    // ---- weight transpose+convert (attention groups merged: z = 72)
    wtr_attn_k<<<dim3(Dm / 32, Dm / 32, 72), 256, 0, stream>>>(
        enc_attn_w, dec_self_w, dec_cross_w, w_enc_attn, w_dec_self, w_dec_cross);
    wtr_k<<<dim3(DFFv / 32, Dm / 32, 6), 256, 0, stream>>>(enc_ffn_w1, w_enc_f1, Dm, DFFv);
    wtr_k<<<dim3(Dm / 32, DFFv / 32, 6), 256, 0, stream>>>(enc_ffn_w2, w_enc_f2, DFFv, Dm);
    wtr_k<<<dim3(DFFv / 32, Dm / 32, 6), 256, 0, stream>>>(dec_ffn_w1, w_dec_f1, Dm, DFFv);
    wtr_k<<<dim3(Dm / 32, DFFv / 32, 6), 256, 0, stream>>>(dec_ffn_w2, w_dec_f2, DFFv, Dm);
    wtr_k<<<dim3(Vv / 32, Dm / 32, 1), 256, 0, stream>>>(out_w, w_out, Dm, Vv);

    auto gqkv = [&](const __bf16* A, const __bf16* Wt, const float* bias) {
        gemm_mfma_k<128, 128, 0, 2><<<dim3(1536 / 128, NTOK / 128), 256, 0, stream>>>(
            A, Wt, bias, qbb, kbb, vbT, NTOK, 1536, Dm);
    };
    auto g64b = [&](const __bf16* A, const __bf16* Wt, const float* bias, __bf16* C, int K) {
        gemm_mfma_k<64, 64, 0, 1><<<dim3(Dm / 64, NTOK / 64), 256, 0, stream>>>(
            A, Wt, bias, C, nullptr, nullptr, NTOK, Dm, K);
    };
    auto attn = [&](const __bf16* Q, const __bf16* K, const __bf16* Vt, __bf16* O,
                    const int* kt, int causal) {
        attn_mfma_k<<<dim3(Ss / 64, Hh, Bb), 256, 0, stream>>>(Q, K, Vt, O, kt, causal);
    };
    auto lnorm = [&](__bf16* xb, const __bf16* ab, const float* g, const float* b) {
        add_ln_b_k<<<NTOK / 4, 256, 0, stream>>>(xb, ab, g, b);
    };

    // embeddings + PE (both streams, one launch)
    embed_pe_k<<<dim3(NTOK, 2), 256, 0, stream>>>(src, tgt, src_emb, tgt_emb, xeb, xdb);

    // ---------------- encoder
    for (int i = 0; i < Ll; ++i) {
        const __bf16* W = w_enc_attn + (size_t)i * 4 * WSZ;
        const float* Bv = enc_attn_b + (size_t)i * 4 * Dm;
        gqkv(xeb, W, Bv);                               // q,k,v (+V transposed)
        attn(qbb, kbb, vbT, ctxb, src, 0);
        g64b(ctxb, W + 3 * WSZ, Bv + 3 * Dm, t0b, Dm);
        lnorm(xeb, t0b, enc_ln_g + i * 2 * Dm, enc_ln_b + i * 2 * Dm);
        gemm_mfma_k<128, 128, 1, 1><<<dim3(DFFv / 128, NTOK / 128), 256, 0, stream>>>(
            xeb, w_enc_f1 + (size_t)i * FSZ, enc_ffn_b1 + i * DFFv, h1b, nullptr, nullptr,
            NTOK, DFFv, Dm);
        g64b(h1b, w_enc_f2 + (size_t)i * FSZ, enc_ffn_b2 + i * Dm, t0b, DFFv);
        lnorm(xeb, t0b, enc_ln_g + i * 2 * Dm + Dm, enc_ln_b + i * 2 * Dm + Dm);
    }

    // ---------------- merged cross-KV for all 6 decoder layers (from memory xeb)
    gemm_mfma_k<128, 128, 0, 4><<<dim3(6144 / 128, NTOK / 128), 256, 0, stream>>>(
        xeb, w_dec_cross, dec_cross_b, nullptr, kbb6, vbT6, NTOK, 6144, Dm);

    // ---------------- decoder
    for (int i = 0; i < Ll; ++i) {
        const __bf16* Wsf = w_dec_self + (size_t)i * 4 * WSZ;
        const float* Bsf = dec_self_b + (size_t)i * 4 * Dm;
        gqkv(xdb, Wsf, Bsf);
        attn(qbb, kbb, vbT, ctxb, tgt, 1);                   // causal + tgt pad
        g64b(ctxb, Wsf + 3 * WSZ, Bsf + 3 * Dm, t0b, Dm);
        lnorm(xdb, t0b, dec_ln_g + i * 3 * Dm, dec_ln_b + i * 3 * Dm);

        const __bf16* Wc = w_dec_cross + (size_t)i * 4 * WSZ;
        const float* Bc = dec_cross_b + (size_t)i * 4 * Dm;
        g64b(xdb, Wc + 0 * WSZ, Bc + 0 * Dm, qbb, Dm);       // Q from post-LN decoder
        attn(qbb, kbb6 + (size_t)i * NROW, vbT6 + (size_t)i * NROW, ctxb, src, 0);
        g64b(ctxb, Wc + 3 * WSZ, Bc + 3 * Dm, t0b, Dm);
        lnorm(xdb, t0b, dec_ln_g + i * 3 * Dm + Dm, dec_ln_b + i * 3 * Dm + Dm);

        gemm_mfma_k<128, 128, 1, 1><<<dim3(DFFv / 128, NTOK / 128), 256, 0, stream>>>(
            xdb, w_dec_f1 + (size_t)i * FSZ, dec_ffn_b1 + i * DFFv, h1b, nullptr, nullptr,
            NTOK, DFFv, Dm);
        g64b(h1b, w_dec_f2 + (size_t)i * FSZ, dec_ffn_b2 + i * Dm, t0b, DFFv);
        lnorm(xdb, t0b, dec_ln_g + i * 3 * Dm + 2 * Dm, dec_ln_b + i * 3 * Dm + 2 * Dm);
    }

    // ---------------- final vocab projection -> d_out [8,512,32000] f32
    gemm256_k<<<dim3(NTOK / 256, Vv / 256), 512, 0, stream>>>(
        xdb, w_out, out_b, (float*)d_out, NTOK, Vv, Dm);
}

// Round 13
// 1966.222 us; speedup vs baseline: 1.0254x; 1.0254x over previous
//
#include <hip/hip_runtime.h>
#include <hip/hip_bf16.h>

// TransformerNMT r12: r10 structure exactly (64x128 QKV tiles, 3 blocks/CU)
// + merged attention-weight transpose (r11's only kept piece).
// B=8, S=T=512, D=512, H=8, hd=64, L=6, DFF=2048, V=32000, PAD=0

#define Dm 512
#define Hh 8
#define HD 64
#define Ll 6
#define DFFv 2048
#define Vv 32000
#define Bb 8
#define Ss 512
#define NTOK (Bb * Ss)   // 4096 rows
#define NROWC ((size_t)NTOK * Dm)   // 2,097,152

typedef __bf16 bf16x8 __attribute__((ext_vector_type(8)));
typedef __bf16 bf16x4 __attribute__((ext_vector_type(4)));
typedef float  f32x4  __attribute__((ext_vector_type(4)));

#define GLOAD16(gp, lp) __builtin_amdgcn_global_load_lds( \
    (const __attribute__((address_space(1))) unsigned int*)(const void*)(gp), \
    (__attribute__((address_space(3))) unsigned int*)(void*)(lp), 16, 0, 0)

// ---------------------------------------------------------------- embed + PE (bf16 out)
__global__ void embed_pe_k(const int* __restrict__ tok_s, const int* __restrict__ tok_t,
                           const float* __restrict__ emb_s, const float* __restrict__ emb_t,
                           __bf16* __restrict__ out_s, __bf16* __restrict__ out_t)
{
    int row = blockIdx.x;
    int s = row & 511;
    const int* tok = blockIdx.y ? tok_t : tok_s;
    const float* emb = blockIdx.y ? emb_t : emb_s;
    __bf16* ob = (blockIdx.y ? out_t : out_s) + (size_t)row * Dm;
    int t = tok[row];
    const float* e = emb + (size_t)t * Dm;
    for (int dd = threadIdx.x; dd < Dm; dd += blockDim.x) {
        int j = dd >> 1;
        float div = expf((float)(2 * j) * (-9.210340371976184f / 512.0f));
        float ang = (float)s * div;
        float pe = (dd & 1) ? cosf(ang) : sinf(ang);
        ob[dd] = (__bf16)(e[dd] * 22.627416997969522f + pe);   // sqrt(512)
    }
}

// ---------------------------------------------------------------- weight transpose+convert
__global__ __launch_bounds__(256) void wtr_k(const float* __restrict__ W,
                                             __bf16* __restrict__ Wt, int K, int N)
{
    __shared__ float t[32][33];
    size_t msz = (size_t)K * N;
    const float* Wm = W + (size_t)blockIdx.z * msz;
    __bf16* Wtm = Wt + (size_t)blockIdx.z * msz;
    int n0 = blockIdx.x * 32, k0 = blockIdx.y * 32;
    int r = threadIdx.x >> 3, c4 = (threadIdx.x & 7) * 4;
    float4 v = *reinterpret_cast<const float4*>(&Wm[(size_t)(k0 + r) * N + n0 + c4]);
    t[r][c4] = v.x; t[r][c4 + 1] = v.y; t[r][c4 + 2] = v.z; t[r][c4 + 3] = v.w;
    __syncthreads();
    int n = threadIdx.x >> 3, kq = (threadIdx.x & 7) * 4;
    bf16x4 o;
    o[0] = (__bf16)t[kq + 0][n]; o[1] = (__bf16)t[kq + 1][n];
    o[2] = (__bf16)t[kq + 2][n]; o[3] = (__bf16)t[kq + 3][n];
    *reinterpret_cast<bf16x4*>(&Wtm[(size_t)(n0 + n) * K + k0 + kq]) = o;
}

// Merged 512x512 attention-weight transpose: z in [0,72), group = z/24
__global__ __launch_bounds__(256) void wtr_attn_k(const float* __restrict__ W0,
                                                  const float* __restrict__ W1,
                                                  const float* __restrict__ W2,
                                                  __bf16* __restrict__ D0,
                                                  __bf16* __restrict__ D1,
                                                  __bf16* __restrict__ D2)
{
    __shared__ float t[32][33];
    int grp = blockIdx.z / 24, mi = blockIdx.z % 24;
    const float* Wm = (grp == 0 ? W0 : grp == 1 ? W1 : W2) + (size_t)mi * Dm * Dm;
    __bf16* Wtm = (grp == 0 ? D0 : grp == 1 ? D1 : D2) + (size_t)mi * Dm * Dm;
    int n0 = blockIdx.x * 32, k0 = blockIdx.y * 32;
    int r = threadIdx.x >> 3, c4 = (threadIdx.x & 7) * 4;
    float4 v = *reinterpret_cast<const float4*>(&Wm[(size_t)(k0 + r) * Dm + n0 + c4]);
    t[r][c4] = v.x; t[r][c4 + 1] = v.y; t[r][c4 + 2] = v.z; t[r][c4 + 3] = v.w;
    __syncthreads();
    int n = threadIdx.x >> 3, kq = (threadIdx.x & 7) * 4;
    bf16x4 o;
    o[0] = (__bf16)t[kq + 0][n]; o[1] = (__bf16)t[kq + 1][n];
    o[2] = (__bf16)t[kq + 2][n]; o[3] = (__bf16)t[kq + 3][n];
    *reinterpret_cast<bf16x4*>(&Wtm[(size_t)(n0 + n) * Dm + k0 + kq]) = o;
}

// ---------------------------------------------------------------- MFMA GEMM (4 waves, BK=64)
// r6-proven 2-slot dbuf, plain __syncthreads, XOR-swizzled LDS.
// MODE 1: bf16 out (+RELU); MODE 2: fused QKV (N=1536);
// MODE 4: merged 6-layer cross-KV (N=6144, weight row = li*2048+512+cw).
template<int BM, int BN, int RELU, int MODE>
__global__ __launch_bounds__(256) void gemm_mfma_k(const __bf16* __restrict__ A,
                                                   const __bf16* __restrict__ Wt,
                                                   const float* __restrict__ bias,
                                                   void* __restrict__ Cout,
                                                   __bf16* __restrict__ out_k,
                                                   __bf16* __restrict__ out_vT,
                                                   int M, int N, int K)
{
    constexpr int NF_M = BM / 32;
    constexpr int NF_N = BN / 32;
    __shared__ __bf16 As[2][BM * 64];
    __shared__ __bf16 Bs[2][BN * 64];
    const int tid = threadIdx.x;
    const int wave = tid >> 6, lane = tid & 63;
    const int wr = wave >> 1, wc = wave & 1;
    const int row0 = blockIdx.y * BM, col0 = blockIdx.x * BN;

    f32x4 acc[NF_M][NF_N] = {};
    const int fr = lane & 15;
    const int kg = lane >> 4;

    auto stage = [&](int buf, int k0) {
        #pragma unroll
        for (int cc = 0; cc < BM / 32; ++cc) {
            int g = cc * 256 + tid;
            int r = g >> 3, gs = (g & 7) ^ (r & 7);
            GLOAD16(A + (size_t)(row0 + r) * K + k0 + gs * 8, &As[buf][g * 8]);
        }
        #pragma unroll
        for (int cc = 0; cc < BN / 32; ++cc) {
            int g = cc * 256 + tid;
            int r = g >> 3, gs = (g & 7) ^ (r & 7);
            int c = col0 + r;
            size_t wrow;
            if constexpr (MODE == 4)
                wrow = (size_t)(c >> 10) * 2048 + 512 + (c & 1023);
            else
                wrow = (size_t)c;
            GLOAD16(Wt + wrow * K + k0 + gs * 8, &Bs[buf][g * 8]);
        }
    };

    stage(0, 0);
    __syncthreads();                     // drains vmcnt -> tile 0 ready

    const int nk = K >> 6;
    for (int kb = 0; kb < nk; ++kb) {
        int cur = kb & 1;
        if (kb + 1 < nk) stage(cur ^ 1, (kb + 1) * 64);   // prefetch in flight

        const char* Ab  = (const char*)As[cur];
        const char* Bbp = (const char*)Bs[cur];
        #pragma unroll
        for (int ks = 0; ks < 2; ++ks) {
            bf16x8 af[NF_M], bq[NF_N];
            #pragma unroll
            for (int m = 0; m < NF_M; ++m) {
                int ar = wr * (BM / 2) + m * 16 + fr;
                af[m] = *reinterpret_cast<const bf16x8*>(
                    Ab + ar * 128 + (((ks * 4 + kg) ^ (ar & 7)) << 4));
            }
            #pragma unroll
            for (int n = 0; n < NF_N; ++n) {
                int br = wc * (BN / 2) + n * 16 + fr;
                bq[n] = *reinterpret_cast<const bf16x8*>(
                    Bbp + br * 128 + (((ks * 4 + kg) ^ (br & 7)) << 4));
            }
            #pragma unroll
            for (int m = 0; m < NF_M; ++m)
                #pragma unroll
                for (int n = 0; n < NF_N; ++n)
                    acc[m][n] = __builtin_amdgcn_mfma_f32_16x16x32_bf16(
                        af[m], bq[n], acc[m][n], 0, 0, 0);
        }
        __syncthreads();                 // prefetch drained + reads done
    }

    #pragma unroll
    for (int m = 0; m < NF_M; ++m) {
        #pragma unroll
        for (int n = 0; n < NF_N; ++n) {
            int colg = col0 + wc * (BN / 2) + n * 16 + fr;
            float bv;
            if constexpr (MODE == 4)
                bv = bias[(colg >> 10) * 2048 + 512 + (colg & 1023)];
            else
                bv = bias[colg];
            #pragma unroll
            for (int j = 0; j < 4; ++j) {
                int row = row0 + wr * (BM / 2) + m * 16 + kg * 4 + j;
                float v = acc[m][n][j] + bv;
                if (RELU) v = fmaxf(v, 0.f);
                if constexpr (MODE == 1) {
                    ((__bf16*)Cout)[(size_t)row * N + colg] = (__bf16)v;
                } else if constexpr (MODE == 2) {
                    int seg = colg >> 9;          // uniform per block
                    int c = colg & 511;
                    if (seg == 0) {
                        ((__bf16*)Cout)[(size_t)row * 512 + c] = (__bf16)v;
                    } else if (seg == 1) {
                        out_k[(size_t)row * 512 + c] = (__bf16)v;
                    } else {
                        int bi = row >> 9, sI = row & 511;
                        int hh = c >> 6, f = c & 63;
                        out_vT[(size_t)((bi * 8 + hh) * 64 + f) * 512 + sI] = (__bf16)v;
                    }
                } else {   // MODE 4: merged cross-KV, layers stacked in N
                    int li = colg >> 10;
                    int cw = colg & 1023;
                    if (cw < 512) {
                        out_k[li * NROWC + (size_t)row * 512 + cw] = (__bf16)v;
                    } else {
                        int hh = (cw - 512) >> 6, f = (cw - 512) & 63;
                        int bi = row >> 9, sI = row & 511;
                        out_vT[li * NROWC +
                               (size_t)((bi * 8 + hh) * 64 + f) * 512 + sI] = (__bf16)v;
                    }
                }
            }
        }
    }
}

// ---------------------------------------------------------------- 256^2 8-wave GEMM (vocab)
__global__ __launch_bounds__(512) void gemm256_k(const __bf16* __restrict__ A,
                                                 const __bf16* __restrict__ Wt,
                                                 const float* __restrict__ bias,
                                                 float* __restrict__ C,
                                                 int M, int N, int K)
{
    __shared__ __bf16 As[2][256 * 64];
    __shared__ __bf16 Bs[2][256 * 64];
    const int tid = threadIdx.x;
    const int wave = tid >> 6, lane = tid & 63;
    const int wr = wave >> 2, wc = wave & 3;     // 2 x 4
    const int row0 = blockIdx.x * 256, col0 = blockIdx.y * 256;

    f32x4 acc[8][4] = {};
    const int fr = lane & 15;
    const int kg = lane >> 4;

    auto stage = [&](int buf, int k0) {
        #pragma unroll
        for (int cc = 0; cc < 4; ++cc) {
            int g = cc * 512 + tid;              // 0..2047
            int r = g >> 3, gs = (g & 7) ^ (r & 7);
            GLOAD16(A + (size_t)(row0 + r) * K + k0 + gs * 8, &As[buf][g * 8]);
        }
        #pragma unroll
        for (int cc = 0; cc < 4; ++cc) {
            int g = cc * 512 + tid;
            int r = g >> 3, gs = (g & 7) ^ (r & 7);
            GLOAD16(Wt + (size_t)(col0 + r) * K + k0 + gs * 8, &Bs[buf][g * 8]);
        }
    };

    stage(0, 0);
    __syncthreads();

    const int nk = K >> 6;
    for (int kb = 0; kb < nk; ++kb) {
        int cur = kb & 1;
        if (kb + 1 < nk) stage(cur ^ 1, (kb + 1) * 64);

        const char* Ab  = (const char*)As[cur];
        const char* Bbp = (const char*)Bs[cur];
        #pragma unroll
        for (int ks = 0; ks < 2; ++ks) {
            bf16x8 af[8], bq[4];
            #pragma unroll
            for (int m = 0; m < 8; ++m) {
                int ar = wr * 128 + m * 16 + fr;
                af[m] = *reinterpret_cast<const bf16x8*>(
                    Ab + ar * 128 + (((ks * 4 + kg) ^ (ar & 7)) << 4));
            }
            #pragma unroll
            for (int n = 0; n < 4; ++n) {
                int br = wc * 64 + n * 16 + fr;
                bq[n] = *reinterpret_cast<const bf16x8*>(
                    Bbp + br * 128 + (((ks * 4 + kg) ^ (br & 7)) << 4));
            }
            #pragma unroll
            for (int m = 0; m < 8; ++m)
                #pragma unroll
                for (int n = 0; n < 4; ++n)
                    acc[m][n] = __builtin_amdgcn_mfma_f32_16x16x32_bf16(
                        af[m], bq[n], acc[m][n], 0, 0, 0);
        }
        __syncthreads();
    }

    #pragma unroll
    for (int m = 0; m < 8; ++m) {
        #pragma unroll
        for (int n = 0; n < 4; ++n) {
            int colg = col0 + wc * 64 + n * 16 + fr;
            float bv = bias[colg];
            #pragma unroll
            for (int j = 0; j < 4; ++j) {
                int row = row0 + wr * 128 + m * 16 + kg * 4 + j;
                C[(size_t)row * N + colg] = acc[m][n][j] + bv;
            }
        }
    }
}

// ---------------------------------------------------------------- MFMA flash attention
__global__ __launch_bounds__(256) void attn_mfma_k(const __bf16* __restrict__ Qb,
                                                   const __bf16* __restrict__ Kb,
                                                   const __bf16* __restrict__ VbT,
                                                   __bf16* __restrict__ Ob,
                                                   const int* __restrict__ key_tok,
                                                   int causal)
{
    __shared__ __bf16 Ks[2][128 * 64];
    __shared__ __bf16 Vs[2][64 * 128];
    __shared__ __bf16 Pl[4][16 * 128];

    const int tid = threadIdx.x;
    const int w = tid >> 6, lane = tid & 63;
    const int fr = lane & 15, kg = lane >> 4;
    const int q0 = blockIdx.x * 64;
    const int h = blockIdx.y, b = blockIdx.z;
    const int qrow = q0 + w * 16 + fr;
    const int swz = (fr & 7) << 4;

    bf16x8 qf[2];
    {
        const __bf16* qp = Qb + ((size_t)(b * 512 + qrow) * 512 + h * 64 + kg * 8);
        qf[0] = *reinterpret_cast<const bf16x8*>(qp);
        qf[1] = *reinterpret_cast<const bf16x8*>(qp + 32);
    }

    f32x4 po[4] = {};
    float m_run = -3.0e38f, l_run = 0.f;
    __bf16* pw = Pl[w];

    auto stage = [&](int buf, int kk0) {
        #pragma unroll
        for (int c = 0; c < 4; ++c) {
            int ch = c * 256 + tid;
            int r = ch >> 3, gsk = (ch & 7) ^ (r & 7);
            GLOAD16(Kb + ((size_t)(b * 512 + kk0 + r) * 512 + h * 64 + gsk * 8),
                    &Ks[buf][ch * 8]);
            int f = ch >> 4, gsv = (ch & 15) ^ (f & 7);
            GLOAD16(VbT + ((size_t)((b * 8 + h) * 64 + f) * 512 + kk0 + gsv * 8),
                    &Vs[buf][ch * 8]);
        }
    };

    const int kkend = causal ? ((q0 + 64 + 127) & ~127) : 512;
    stage(0, 0);
    __syncthreads();

    for (int kk0 = 0; kk0 < kkend; kk0 += 128) {
        int cur = (kk0 >> 7) & 1;
        if (kk0 + 128 < kkend) stage(cur ^ 1, kk0 + 128);

        unsigned long long vm0 = __ballot(key_tok[b * 512 + kk0 + lane] != 0);
        unsigned long long vm1 = __ballot(key_tok[b * 512 + kk0 + 64 + lane] != 0);

        f32x4 st[8];
        #pragma unroll
        for (int kt = 0; kt < 8; ++kt) {
            f32x4 s = {};
            #pragma unroll
            for (int ks = 0; ks < 2; ++ks) {
                int byte = ((kt * 16 + fr) * 128 + ks * 64 + kg * 16) ^ swz;
                bf16x8 kf = *reinterpret_cast<const bf16x8*>((const char*)Ks[cur] + byte);
                s = __builtin_amdgcn_mfma_f32_16x16x32_bf16(kf, qf[ks], s, 0, 0, 0);
            }
            st[kt] = s;
        }

        float sv[8][4];
        float mloc = -3.0e38f;
        #pragma unroll
        for (int kt = 0; kt < 8; ++kt) {
            unsigned long long vm = (kt < 4) ? vm0 : vm1;
            #pragma unroll
            for (int j = 0; j < 4; ++j) {
                int kl = kt * 16 + kg * 4 + j;
                float s = st[kt][j] * 0.125f;
                bool ok = (vm >> (kl & 63)) & 1ull;
                if (causal && (kk0 + kl > qrow)) ok = false;
                s = ok ? s : -1e9f;
                sv[kt][j] = s;
                mloc = fmaxf(mloc, s);
            }
        }
        mloc = fmaxf(mloc, __shfl_xor(mloc, 16));
        mloc = fmaxf(mloc, __shfl_xor(mloc, 32));
        float m_new = fmaxf(m_run, mloc);
        float scale = __expf(m_run - m_new);
        float ls = 0.f;
        #pragma unroll
        for (int kt = 0; kt < 8; ++kt)
            #pragma unroll
            for (int j = 0; j < 4; ++j) {
                float p = __expf(sv[kt][j] - m_new);
                sv[kt][j] = p;
                ls += p;
            }
        ls += __shfl_xor(ls, 16);
        ls += __shfl_xor(ls, 32);
        l_run = l_run * scale + ls;
        m_run = m_new;

        #pragma unroll
        for (int kt = 0; kt < 8; ++kt)
            #pragma unroll
            for (int c = 0; c < 2; ++c) {
                union { __bf16 hh[2]; unsigned u; } pk;
                pk.hh[0] = (__bf16)sv[kt][2 * c];
                pk.hh[1] = (__bf16)sv[kt][2 * c + 1];
                int byte = (fr * 256 + kt * 32 + kg * 8 + c * 4) ^ swz;
                *reinterpret_cast<unsigned*>((char*)pw + byte) = pk.u;
            }

        {
            int qb4 = kg * 4;
            float s0 = __shfl(scale, qb4 + 0), s1 = __shfl(scale, qb4 + 1);
            float s2 = __shfl(scale, qb4 + 2), s3 = __shfl(scale, qb4 + 3);
            #pragma unroll
            for (int nf = 0; nf < 4; ++nf) {
                po[nf][0] *= s0; po[nf][1] *= s1;
                po[nf][2] *= s2; po[nf][3] *= s3;
            }
        }

        #pragma unroll
        for (int ks2 = 0; ks2 < 4; ++ks2) {
            int pbyte = (fr * 256 + ks2 * 64 + kg * 16) ^ swz;
            bf16x8 pa = *reinterpret_cast<const bf16x8*>((const char*)pw + pbyte);
            #pragma unroll
            for (int nf = 0; nf < 4; ++nf) {
                int vbyte = ((nf * 16 + fr) * 256 + ks2 * 64 + kg * 16) ^ swz;
                bf16x8 vf = *reinterpret_cast<const bf16x8*>((const char*)Vs[cur] + vbyte);
                po[nf] = __builtin_amdgcn_mfma_f32_16x16x32_bf16(pa, vf, po[nf], 0, 0, 0);
            }
        }
        __syncthreads();
    }

    {
        int qb4 = kg * 4;
        float r0 = 1.0f / __shfl(l_run, qb4 + 0);
        float r1 = 1.0f / __shfl(l_run, qb4 + 1);
        float r2 = 1.0f / __shfl(l_run, qb4 + 2);
        float r3 = 1.0f / __shfl(l_run, qb4 + 3);
        #pragma unroll
        for (int nf = 0; nf < 4; ++nf) {
            size_t base = (size_t)(b * 512 + q0 + w * 16 + qb4) * 512 + h * 64 + nf * 16 + fr;
            Ob[base]           = (__bf16)(po[nf][0] * r0);
            Ob[base + 512]     = (__bf16)(po[nf][1] * r1);
            Ob[base + 1024]    = (__bf16)(po[nf][2] * r2);
            Ob[base + 1536]    = (__bf16)(po[nf][3] * r3);
        }
    }
}

// ---------------------------------------------------------------- residual + LN, bf16 stream
__global__ __launch_bounds__(256) void add_ln_b_k(__bf16* __restrict__ xb,
                                                  const __bf16* __restrict__ ab,
                                                  const float* __restrict__ g,
                                                  const float* __restrict__ bb)
{
    const int w = threadIdx.x >> 6, lane = threadIdx.x & 63;
    const int row = blockIdx.x * 4 + w;
    const size_t base = (size_t)row * Dm + lane * 8;
    bf16x8 xv = *reinterpret_cast<const bf16x8*>(&xb[base]);
    bf16x8 av = *reinterpret_cast<const bf16x8*>(&ab[base]);
    float v[8];
    float s = 0.f, s2 = 0.f;
    #pragma unroll
    for (int j = 0; j < 8; ++j) {
        v[j] = (float)xv[j] + (float)av[j];
        s += v[j];
        s2 += v[j] * v[j];
    }
    #pragma unroll
    for (int o = 1; o < 64; o <<= 1) {
        s  += __shfl_xor(s, o);
        s2 += __shfl_xor(s2, o);
    }
    float mean = s * (1.0f / 512.0f);
    float var  = s2 * (1.0f / 512.0f) - mean * mean;
    float rstd = rsqrtf(var + 1e-5f);
    float4 g0 = *reinterpret_cast<const float4*>(&g[lane * 8]);
    float4 g1 = *reinterpret_cast<const float4*>(&g[lane * 8 + 4]);
    float4 b0 = *reinterpret_cast<const float4*>(&bb[lane * 8]);
    float4 b1 = *reinterpret_cast<const float4*>(&bb[lane * 8 + 4]);
    float gv[8] = {g0.x, g0.y, g0.z, g0.w, g1.x, g1.y, g1.z, g1.w};
    float bv[8] = {b0.x, b0.y, b0.z, b0.w, b1.x, b1.y, b1.z, b1.w};
    bf16x8 yv;
    #pragma unroll
    for (int j = 0; j < 8; ++j)
        yv[j] = (__bf16)((v[j] - mean) * rstd * gv[j] + bv[j]);
    *reinterpret_cast<bf16x8*>(&xb[base]) = yv;
}

// ---------------------------------------------------------------- launch
extern "C" void kernel_launch(void* const* d_in, const int* in_sizes, int n_in,
                              void* d_out, int out_size, void* d_ws, size_t ws_size,
                              hipStream_t stream)
{
    const int*   src        = (const int*)  d_in[0];
    const int*   tgt        = (const int*)  d_in[1];
    const float* src_emb    = (const float*)d_in[2];
    const float* tgt_emb    = (const float*)d_in[3];
    const float* enc_attn_w = (const float*)d_in[4];
    const float* enc_attn_b = (const float*)d_in[5];
    const float* enc_ffn_w1 = (const float*)d_in[6];
    const float* enc_ffn_b1 = (const float*)d_in[7];
    const float* enc_ffn_w2 = (const float*)d_in[8];
    const float* enc_ffn_b2 = (const float*)d_in[9];
    const float* enc_ln_g   = (const float*)d_in[10];
    const float* enc_ln_b   = (const float*)d_in[11];
    const float* dec_self_w = (const float*)d_in[12];
    const float* dec_self_b = (const float*)d_in[13];
    const float* dec_cross_w= (const float*)d_in[14];
    const float* dec_cross_b= (const float*)d_in[15];
    const float* dec_ffn_w1 = (const float*)d_in[16];
    const float* dec_ffn_b1 = (const float*)d_in[17];
    const float* dec_ffn_w2 = (const float*)d_in[18];
    const float* dec_ffn_b2 = (const float*)d_in[19];
    const float* dec_ln_g   = (const float*)d_in[20];
    const float* dec_ln_b   = (const float*)d_in[21];
    const float* out_w      = (const float*)d_in[22];
    const float* out_b      = (const float*)d_in[23];

    const size_t NROW = NROWC;                    // 2,097,152
    const size_t NH1  = (size_t)NTOK * DFFv;      // 8,388,608

    __bf16* xeb  = (__bf16*)d_ws;         // bf16 encoder stream
    __bf16* xdb  = xeb + NROW;            // bf16 decoder stream
    __bf16* t0b  = xdb + NROW;            // bf16 sublayer output (pre-LN)
    __bf16* qbb  = t0b + NROW;
    __bf16* kbb  = qbb + NROW;
    __bf16* vbT  = kbb + NROW;            // [(b*8+h)*64+f][512]
    __bf16* ctxb = vbT + NROW;
    __bf16* h1b  = ctxb + NROW;           // [4096,2048] bf16
    __bf16* kbb6 = h1b + NH1;             // 6 layers cross-K
    __bf16* vbT6 = kbb6 + 6 * NROW;       // 6 layers cross-V (transposed)

    const size_t WSZ  = (size_t)Dm * Dm;          // 262144
    const size_t FSZ  = (size_t)Dm * DFFv;        // 1048576
    __bf16* w_enc_attn = vbT6 + 6 * NROW;
    __bf16* w_enc_f1   = w_enc_attn + 24 * WSZ;
    __bf16* w_enc_f2   = w_enc_f1 + 6 * FSZ;
    __bf16* w_dec_self = w_enc_f2 + 6 * FSZ;
    __bf16* w_dec_cross= w_dec_self + 24 * WSZ;
    __bf16* w_dec_f1   = w_dec_cross + 24 * WSZ;
    __bf16* w_dec_f2   = w_dec_f1 + 6 * FSZ;
    __bf16* w_out      = w_dec_f2 + 6 * FSZ;      // 512*32000

    // ---- weight transpose+convert (attention groups merged: z = 72)
    wtr_attn_k<<<dim3(Dm / 32, Dm / 32, 72), 256, 0, stream>>>(
        enc_attn_w, dec_self_w, dec_cross_w, w_enc_attn, w_dec_self, w_dec_cross);
    wtr_k<<<dim3(DFFv / 32, Dm / 32, 6), 256, 0, stream>>>(enc_ffn_w1, w_enc_f1, Dm, DFFv);
    wtr_k<<<dim3(Dm / 32, DFFv / 32, 6), 256, 0, stream>>>(enc_ffn_w2, w_enc_f2, DFFv, Dm);
    wtr_k<<<dim3(DFFv / 32, Dm / 32, 6), 256, 0, stream>>>(dec_ffn_w1, w_dec_f1, Dm, DFFv);
    wtr_k<<<dim3(Dm / 32, DFFv / 32, 6), 256, 0, stream>>>(dec_ffn_w2, w_dec_f2, DFFv, Dm);
    wtr_k<<<dim3(Vv / 32, Dm / 32, 1), 256, 0, stream>>>(out_w, w_out, Dm, Vv);

    auto gqkv = [&](const __bf16* A, const __bf16* Wt, const float* bias) {
        gemm_mfma_k<64, 128, 0, 2><<<dim3(1536 / 128, NTOK / 64), 256, 0, stream>>>(
            A, Wt, bias, qbb, kbb, vbT, NTOK, 1536, Dm);
    };
    auto g64b = [&](const __bf16* A, const __bf16* Wt, const float* bias, __bf16* C, int K) {
        gemm_mfma_k<64, 64, 0, 1><<<dim3(Dm / 64, NTOK / 64), 256, 0, stream>>>(
            A, Wt, bias, C, nullptr, nullptr, NTOK, Dm, K);
    };
    auto attn = [&](const __bf16* Q, const __bf16* K, const __bf16* Vt, __bf16* O,
                    const int* kt, int causal) {
        attn_mfma_k<<<dim3(Ss / 64, Hh, Bb), 256, 0, stream>>>(Q, K, Vt, O, kt, causal);
    };
    auto lnorm = [&](__bf16* xb, const __bf16* ab, const float* g, const float* b) {
        add_ln_b_k<<<NTOK / 4, 256, 0, stream>>>(xb, ab, g, b);
    };

    // embeddings + PE (both streams, one launch)
    embed_pe_k<<<dim3(NTOK, 2), 256, 0, stream>>>(src, tgt, src_emb, tgt_emb, xeb, xdb);

    // ---------------- encoder
    for (int i = 0; i < Ll; ++i) {
        const __bf16* W = w_enc_attn + (size_t)i * 4 * WSZ;
        const float* Bv = enc_attn_b + (size_t)i * 4 * Dm;
        gqkv(xeb, W, Bv);                               // q,k,v (+V transposed)
        attn(qbb, kbb, vbT, ctxb, src, 0);
        g64b(ctxb, W + 3 * WSZ, Bv + 3 * Dm, t0b, Dm);
        lnorm(xeb, t0b, enc_ln_g + i * 2 * Dm, enc_ln_b + i * 2 * Dm);
        gemm_mfma_k<128, 128, 1, 1><<<dim3(DFFv / 128, NTOK / 128), 256, 0, stream>>>(
            xeb, w_enc_f1 + (size_t)i * FSZ, enc_ffn_b1 + i * DFFv, h1b, nullptr, nullptr,
            NTOK, DFFv, Dm);
        g64b(h1b, w_enc_f2 + (size_t)i * FSZ, enc_ffn_b2 + i * Dm, t0b, DFFv);
        lnorm(xeb, t0b, enc_ln_g + i * 2 * Dm + Dm, enc_ln_b + i * 2 * Dm + Dm);
    }

    // ---------------- merged cross-KV for all 6 decoder layers (from memory xeb)
    gemm_mfma_k<64, 128, 0, 4><<<dim3(6144 / 128, NTOK / 64), 256, 0, stream>>>(
        xeb, w_dec_cross, dec_cross_b, nullptr, kbb6, vbT6, NTOK, 6144, Dm);

    // ---------------- decoder
    for (int i = 0; i < Ll; ++i) {
        const __bf16* Wsf = w_dec_self + (size_t)i * 4 * WSZ;
        const float* Bsf = dec_self_b + (size_t)i * 4 * Dm;
        gqkv(xdb, Wsf, Bsf);
        attn(qbb, kbb, vbT, ctxb, tgt, 1);                   // causal + tgt pad
        g64b(ctxb, Wsf + 3 * WSZ, Bsf + 3 * Dm, t0b, Dm);
        lnorm(xdb, t0b, dec_ln_g + i * 3 * Dm, dec_ln_b + i * 3 * Dm);

        const __bf16* Wc = w_dec_cross + (size_t)i * 4 * WSZ;
        const float* Bc = dec_cross_b + (size_t)i * 4 * Dm;
        g64b(xdb, Wc + 0 * WSZ, Bc + 0 * Dm, qbb, Dm);       // Q from post-LN decoder
        attn(qbb, kbb6 + (size_t)i * NROW, vbT6 + (size_t)i * NROW, ctxb, src, 0);
        g64b(ctxb, Wc + 3 * WSZ, Bc + 3 * Dm, t0b, Dm);
        lnorm(xdb, t0b, dec_ln_g + i * 3 * Dm + Dm, dec_ln_b + i * 3 * Dm + Dm);

        gemm_mfma_k<128, 128, 1, 1><<<dim3(DFFv / 128, NTOK / 128), 256, 0, stream>>>(
            xdb, w_dec_f1 + (size_t)i * FSZ, dec_ffn_b1 + i * DFFv, h1b, nullptr, nullptr,
            NTOK, DFFv, Dm);
        g64b(h1b, w_dec_f2 + (size_t)i * FSZ, dec_ffn_b2 + i * Dm, t0b, DFFv);
        lnorm(xdb, t0b, dec_ln_g + i * 3 * Dm + 2 * Dm, dec_ln_b + i * 3 * Dm + 2 * Dm);
    }

    // ---------------- final vocab projection -> d_out [8,512,32000] f32
    gemm256_k<<<dim3(NTOK / 256, Vv / 256), 512, 0, stream>>>(
        xdb, w_out, out_b, (float*)d_out, NTOK, Vv, Dm);
}

// Round 14
// 1940.589 us; speedup vs baseline: 1.0390x; 1.0132x over previous
//
#include <hip/hip_runtime.h>
#include <hip/hip_bf16.h>

// TransformerNMT r13: r12 + bijective XCD swizzle on vocab GEMM (T1; grid
// 2000 = 8 x 250, each XCD owns ~16 N-panels ~= its 4MB private L2) and
// merged FFN weight-transpose launches (z=12 enc/dec select).
// B=8, S=T=512, D=512, H=8, hd=64, L=6, DFF=2048, V=32000, PAD=0

#define Dm 512
#define Hh 8
#define HD 64
#define Ll 6
#define DFFv 2048
#define Vv 32000
#define Bb 8
#define Ss 512
#define NTOK (Bb * Ss)   // 4096 rows
#define NROWC ((size_t)NTOK * Dm)   // 2,097,152

typedef __bf16 bf16x8 __attribute__((ext_vector_type(8)));
typedef __bf16 bf16x4 __attribute__((ext_vector_type(4)));
typedef float  f32x4  __attribute__((ext_vector_type(4)));

#define GLOAD16(gp, lp) __builtin_amdgcn_global_load_lds( \
    (const __attribute__((address_space(1))) unsigned int*)(const void*)(gp), \
    (__attribute__((address_space(3))) unsigned int*)(void*)(lp), 16, 0, 0)

// ---------------------------------------------------------------- embed + PE (bf16 out)
__global__ void embed_pe_k(const int* __restrict__ tok_s, const int* __restrict__ tok_t,
                           const float* __restrict__ emb_s, const float* __restrict__ emb_t,
                           __bf16* __restrict__ out_s, __bf16* __restrict__ out_t)
{
    int row = blockIdx.x;
    int s = row & 511;
    const int* tok = blockIdx.y ? tok_t : tok_s;
    const float* emb = blockIdx.y ? emb_t : emb_s;
    __bf16* ob = (blockIdx.y ? out_t : out_s) + (size_t)row * Dm;
    int t = tok[row];
    const float* e = emb + (size_t)t * Dm;
    for (int dd = threadIdx.x; dd < Dm; dd += blockDim.x) {
        int j = dd >> 1;
        float div = expf((float)(2 * j) * (-9.210340371976184f / 512.0f));
        float ang = (float)s * div;
        float pe = (dd & 1) ? cosf(ang) : sinf(ang);
        ob[dd] = (__bf16)(e[dd] * 22.627416997969522f + pe);   // sqrt(512)
    }
}

// ---------------------------------------------------------------- weight transpose+convert
__global__ __launch_bounds__(256) void wtr_k(const float* __restrict__ W,
                                             __bf16* __restrict__ Wt, int K, int N)
{
    __shared__ float t[32][33];
    size_t msz = (size_t)K * N;
    const float* Wm = W + (size_t)blockIdx.z * msz;
    __bf16* Wtm = Wt + (size_t)blockIdx.z * msz;
    int n0 = blockIdx.x * 32, k0 = blockIdx.y * 32;
    int r = threadIdx.x >> 3, c4 = (threadIdx.x & 7) * 4;
    float4 v = *reinterpret_cast<const float4*>(&Wm[(size_t)(k0 + r) * N + n0 + c4]);
    t[r][c4] = v.x; t[r][c4 + 1] = v.y; t[r][c4 + 2] = v.z; t[r][c4 + 3] = v.w;
    __syncthreads();
    int n = threadIdx.x >> 3, kq = (threadIdx.x & 7) * 4;
    bf16x4 o;
    o[0] = (__bf16)t[kq + 0][n]; o[1] = (__bf16)t[kq + 1][n];
    o[2] = (__bf16)t[kq + 2][n]; o[3] = (__bf16)t[kq + 3][n];
    *reinterpret_cast<bf16x4*>(&Wtm[(size_t)(n0 + n) * K + k0 + kq]) = o;
}

// Two 6-matrix groups (enc/dec) in one launch: z in [0,12), group = z/6
__global__ __launch_bounds__(256) void wtr2_k(const float* __restrict__ Wa,
                                              const float* __restrict__ Wb,
                                              __bf16* __restrict__ Da,
                                              __bf16* __restrict__ Db, int K, int N)
{
    __shared__ float t[32][33];
    size_t msz = (size_t)K * N;
    int grp = blockIdx.z / 6, mi = blockIdx.z % 6;
    const float* Wm = (grp ? Wb : Wa) + (size_t)mi * msz;
    __bf16* Wtm = (grp ? Db : Da) + (size_t)mi * msz;
    int n0 = blockIdx.x * 32, k0 = blockIdx.y * 32;
    int r = threadIdx.x >> 3, c4 = (threadIdx.x & 7) * 4;
    float4 v = *reinterpret_cast<const float4*>(&Wm[(size_t)(k0 + r) * N + n0 + c4]);
    t[r][c4] = v.x; t[r][c4 + 1] = v.y; t[r][c4 + 2] = v.z; t[r][c4 + 3] = v.w;
    __syncthreads();
    int n = threadIdx.x >> 3, kq = (threadIdx.x & 7) * 4;
    bf16x4 o;
    o[0] = (__bf16)t[kq + 0][n]; o[1] = (__bf16)t[kq + 1][n];
    o[2] = (__bf16)t[kq + 2][n]; o[3] = (__bf16)t[kq + 3][n];
    *reinterpret_cast<bf16x4*>(&Wtm[(size_t)(n0 + n) * K + k0 + kq]) = o;
}

// Merged 512x512 attention-weight transpose: z in [0,72), group = z/24
__global__ __launch_bounds__(256) void wtr_attn_k(const float* __restrict__ W0,
                                                  const float* __restrict__ W1,
                                                  const float* __restrict__ W2,
                                                  __bf16* __restrict__ D0,
                                                  __bf16* __restrict__ D1,
                                                  __bf16* __restrict__ D2)
{
    __shared__ float t[32][33];
    int grp = blockIdx.z / 24, mi = blockIdx.z % 24;
    const float* Wm = (grp == 0 ? W0 : grp == 1 ? W1 : W2) + (size_t)mi * Dm * Dm;
    __bf16* Wtm = (grp == 0 ? D0 : grp == 1 ? D1 : D2) + (size_t)mi * Dm * Dm;
    int n0 = blockIdx.x * 32, k0 = blockIdx.y * 32;
    int r = threadIdx.x >> 3, c4 = (threadIdx.x & 7) * 4;
    float4 v = *reinterpret_cast<const float4*>(&Wm[(size_t)(k0 + r) * Dm + n0 + c4]);
    t[r][c4] = v.x; t[r][c4 + 1] = v.y; t[r][c4 + 2] = v.z; t[r][c4 + 3] = v.w;
    __syncthreads();
    int n = threadIdx.x >> 3, kq = (threadIdx.x & 7) * 4;
    bf16x4 o;
    o[0] = (__bf16)t[kq + 0][n]; o[1] = (__bf16)t[kq + 1][n];
    o[2] = (__bf16)t[kq + 2][n]; o[3] = (__bf16)t[kq + 3][n];
    *reinterpret_cast<bf16x4*>(&Wtm[(size_t)(n0 + n) * Dm + k0 + kq]) = o;
}

// ---------------------------------------------------------------- MFMA GEMM (4 waves, BK=64)
// r6-proven 2-slot dbuf, plain __syncthreads, XOR-swizzled LDS.
// MODE 1: bf16 out (+RELU); MODE 2: fused QKV (N=1536);
// MODE 4: merged 6-layer cross-KV (N=6144, weight row = li*2048+512+cw).
template<int BM, int BN, int RELU, int MODE>
__global__ __launch_bounds__(256) void gemm_mfma_k(const __bf16* __restrict__ A,
                                                   const __bf16* __restrict__ Wt,
                                                   const float* __restrict__ bias,
                                                   void* __restrict__ Cout,
                                                   __bf16* __restrict__ out_k,
                                                   __bf16* __restrict__ out_vT,
                                                   int M, int N, int K)
{
    constexpr int NF_M = BM / 32;
    constexpr int NF_N = BN / 32;
    __shared__ __bf16 As[2][BM * 64];
    __shared__ __bf16 Bs[2][BN * 64];
    const int tid = threadIdx.x;
    const int wave = tid >> 6, lane = tid & 63;
    const int wr = wave >> 1, wc = wave & 1;
    const int row0 = blockIdx.y * BM, col0 = blockIdx.x * BN;

    f32x4 acc[NF_M][NF_N] = {};
    const int fr = lane & 15;
    const int kg = lane >> 4;

    auto stage = [&](int buf, int k0) {
        #pragma unroll
        for (int cc = 0; cc < BM / 32; ++cc) {
            int g = cc * 256 + tid;
            int r = g >> 3, gs = (g & 7) ^ (r & 7);
            GLOAD16(A + (size_t)(row0 + r) * K + k0 + gs * 8, &As[buf][g * 8]);
        }
        #pragma unroll
        for (int cc = 0; cc < BN / 32; ++cc) {
            int g = cc * 256 + tid;
            int r = g >> 3, gs = (g & 7) ^ (r & 7);
            int c = col0 + r;
            size_t wrow;
            if constexpr (MODE == 4)
                wrow = (size_t)(c >> 10) * 2048 + 512 + (c & 1023);
            else
                wrow = (size_t)c;
            GLOAD16(Wt + wrow * K + k0 + gs * 8, &Bs[buf][g * 8]);
        }
    };

    stage(0, 0);
    __syncthreads();                     // drains vmcnt -> tile 0 ready

    const int nk = K >> 6;
    for (int kb = 0; kb < nk; ++kb) {
        int cur = kb & 1;
        if (kb + 1 < nk) stage(cur ^ 1, (kb + 1) * 64);   // prefetch in flight

        const char* Ab  = (const char*)As[cur];
        const char* Bbp = (const char*)Bs[cur];
        #pragma unroll
        for (int ks = 0; ks < 2; ++ks) {
            bf16x8 af[NF_M], bq[NF_N];
            #pragma unroll
            for (int m = 0; m < NF_M; ++m) {
                int ar = wr * (BM / 2) + m * 16 + fr;
                af[m] = *reinterpret_cast<const bf16x8*>(
                    Ab + ar * 128 + (((ks * 4 + kg) ^ (ar & 7)) << 4));
            }
            #pragma unroll
            for (int n = 0; n < NF_N; ++n) {
                int br = wc * (BN / 2) + n * 16 + fr;
                bq[n] = *reinterpret_cast<const bf16x8*>(
                    Bbp + br * 128 + (((ks * 4 + kg) ^ (br & 7)) << 4));
            }
            #pragma unroll
            for (int m = 0; m < NF_M; ++m)
                #pragma unroll
                for (int n = 0; n < NF_N; ++n)
                    acc[m][n] = __builtin_amdgcn_mfma_f32_16x16x32_bf16(
                        af[m], bq[n], acc[m][n], 0, 0, 0);
        }
        __syncthreads();                 // prefetch drained + reads done
    }

    #pragma unroll
    for (int m = 0; m < NF_M; ++m) {
        #pragma unroll
        for (int n = 0; n < NF_N; ++n) {
            int colg = col0 + wc * (BN / 2) + n * 16 + fr;
            float bv;
            if constexpr (MODE == 4)
                bv = bias[(colg >> 10) * 2048 + 512 + (colg & 1023)];
            else
                bv = bias[colg];
            #pragma unroll
            for (int j = 0; j < 4; ++j) {
                int row = row0 + wr * (BM / 2) + m * 16 + kg * 4 + j;
                float v = acc[m][n][j] + bv;
                if (RELU) v = fmaxf(v, 0.f);
                if constexpr (MODE == 1) {
                    ((__bf16*)Cout)[(size_t)row * N + colg] = (__bf16)v;
                } else if constexpr (MODE == 2) {
                    int seg = colg >> 9;          // uniform per block
                    int c = colg & 511;
                    if (seg == 0) {
                        ((__bf16*)Cout)[(size_t)row * 512 + c] = (__bf16)v;
                    } else if (seg == 1) {
                        out_k[(size_t)row * 512 + c] = (__bf16)v;
                    } else {
                        int bi = row >> 9, sI = row & 511;
                        int hh = c >> 6, f = c & 63;
                        out_vT[(size_t)((bi * 8 + hh) * 64 + f) * 512 + sI] = (__bf16)v;
                    }
                } else {   // MODE 4: merged cross-KV, layers stacked in N
                    int li = colg >> 10;
                    int cw = colg & 1023;
                    if (cw < 512) {
                        out_k[li * NROWC + (size_t)row * 512 + cw] = (__bf16)v;
                    } else {
                        int hh = (cw - 512) >> 6, f = (cw - 512) & 63;
                        int bi = row >> 9, sI = row & 511;
                        out_vT[li * NROWC +
                               (size_t)((bi * 8 + hh) * 64 + f) * 512 + sI] = (__bf16)v;
                    }
                }
            }
        }
    }
}

// ---------------------------------------------------------------- 256^2 8-wave GEMM (vocab)
// 1D grid 2000 blocks; bijective XCD swizzle (2000 % 8 == 0): XCD x owns a
// contiguous orig chunk -> its ~16 N-panels (~4 MB of W) stay in its L2.
// M-fastest within chunk (orig&15 = M-tile).
__global__ __launch_bounds__(512) void gemm256_k(const __bf16* __restrict__ A,
                                                 const __bf16* __restrict__ Wt,
                                                 const float* __restrict__ bias,
                                                 float* __restrict__ C,
                                                 int M, int N, int K)
{
    __shared__ __bf16 As[2][256 * 64];
    __shared__ __bf16 Bs[2][256 * 64];
    const int tid = threadIdx.x;
    const int wave = tid >> 6, lane = tid & 63;
    const int wr = wave >> 2, wc = wave & 3;     // 2 x 4
    const int cpx = gridDim.x >> 3;              // chunk per XCD (2000/8 = 250)
    const int orig = (blockIdx.x & 7) * cpx + (blockIdx.x >> 3);
    const int row0 = (orig & 15) * 256;          // 16 M-tiles, fastest
    const int col0 = (orig >> 4) * 256;          // 125 N-panels

    f32x4 acc[8][4] = {};
    const int fr = lane & 15;
    const int kg = lane >> 4;

    auto stage = [&](int buf, int k0) {
        #pragma unroll
        for (int cc = 0; cc < 4; ++cc) {
            int g = cc * 512 + tid;              // 0..2047
            int r = g >> 3, gs = (g & 7) ^ (r & 7);
            GLOAD16(A + (size_t)(row0 + r) * K + k0 + gs * 8, &As[buf][g * 8]);
        }
        #pragma unroll
        for (int cc = 0; cc < 4; ++cc) {
            int g = cc * 512 + tid;
            int r = g >> 3, gs = (g & 7) ^ (r & 7);
            GLOAD16(Wt + (size_t)(col0 + r) * K + k0 + gs * 8, &Bs[buf][g * 8]);
        }
    };

    stage(0, 0);
    __syncthreads();

    const int nk = K >> 6;
    for (int kb = 0; kb < nk; ++kb) {
        int cur = kb & 1;
        if (kb + 1 < nk) stage(cur ^ 1, (kb + 1) * 64);

        const char* Ab  = (const char*)As[cur];
        const char* Bbp = (const char*)Bs[cur];
        #pragma unroll
        for (int ks = 0; ks < 2; ++ks) {
            bf16x8 af[8], bq[4];
            #pragma unroll
            for (int m = 0; m < 8; ++m) {
                int ar = wr * 128 + m * 16 + fr;
                af[m] = *reinterpret_cast<const bf16x8*>(
                    Ab + ar * 128 + (((ks * 4 + kg) ^ (ar & 7)) << 4));
            }
            #pragma unroll
            for (int n = 0; n < 4; ++n) {
                int br = wc * 64 + n * 16 + fr;
                bq[n] = *reinterpret_cast<const bf16x8*>(
                    Bbp + br * 128 + (((ks * 4 + kg) ^ (br & 7)) << 4));
            }
            #pragma unroll
            for (int m = 0; m < 8; ++m)
                #pragma unroll
                for (int n = 0; n < 4; ++n)
                    acc[m][n] = __builtin_amdgcn_mfma_f32_16x16x32_bf16(
                        af[m], bq[n], acc[m][n], 0, 0, 0);
        }
        __syncthreads();
    }

    #pragma unroll
    for (int m = 0; m < 8; ++m) {
        #pragma unroll
        for (int n = 0; n < 4; ++n) {
            int colg = col0 + wc * 64 + n * 16 + fr;
            float bv = bias[colg];
            #pragma unroll
            for (int j = 0; j < 4; ++j) {
                int row = row0 + wr * 128 + m * 16 + kg * 4 + j;
                C[(size_t)row * N + colg] = acc[m][n][j] + bv;
            }
        }
    }
}

// ---------------------------------------------------------------- MFMA flash attention
__global__ __launch_bounds__(256) void attn_mfma_k(const __bf16* __restrict__ Qb,
                                                   const __bf16* __restrict__ Kb,
                                                   const __bf16* __restrict__ VbT,
                                                   __bf16* __restrict__ Ob,
                                                   const int* __restrict__ key_tok,
                                                   int causal)
{
    __shared__ __bf16 Ks[2][128 * 64];
    __shared__ __bf16 Vs[2][64 * 128];
    __shared__ __bf16 Pl[4][16 * 128];

    const int tid = threadIdx.x;
    const int w = tid >> 6, lane = tid & 63;
    const int fr = lane & 15, kg = lane >> 4;
    const int q0 = blockIdx.x * 64;
    const int h = blockIdx.y, b = blockIdx.z;
    const int qrow = q0 + w * 16 + fr;
    const int swz = (fr & 7) << 4;

    bf16x8 qf[2];
    {
        const __bf16* qp = Qb + ((size_t)(b * 512 + qrow) * 512 + h * 64 + kg * 8);
        qf[0] = *reinterpret_cast<const bf16x8*>(qp);
        qf[1] = *reinterpret_cast<const bf16x8*>(qp + 32);
    }

    f32x4 po[4] = {};
    float m_run = -3.0e38f, l_run = 0.f;
    __bf16* pw = Pl[w];

    auto stage = [&](int buf, int kk0) {
        #pragma unroll
        for (int c = 0; c < 4; ++c) {
            int ch = c * 256 + tid;
            int r = ch >> 3, gsk = (ch & 7) ^ (r & 7);
            GLOAD16(Kb + ((size_t)(b * 512 + kk0 + r) * 512 + h * 64 + gsk * 8),
                    &Ks[buf][ch * 8]);
            int f = ch >> 4, gsv = (ch & 15) ^ (f & 7);
            GLOAD16(VbT + ((size_t)((b * 8 + h) * 64 + f) * 512 + kk0 + gsv * 8),
                    &Vs[buf][ch * 8]);
        }
    };

    const int kkend = causal ? ((q0 + 64 + 127) & ~127) : 512;
    stage(0, 0);
    __syncthreads();

    for (int kk0 = 0; kk0 < kkend; kk0 += 128) {
        int cur = (kk0 >> 7) & 1;
        if (kk0 + 128 < kkend) stage(cur ^ 1, kk0 + 128);

        unsigned long long vm0 = __ballot(key_tok[b * 512 + kk0 + lane] != 0);
        unsigned long long vm1 = __ballot(key_tok[b * 512 + kk0 + 64 + lane] != 0);

        f32x4 st[8];
        #pragma unroll
        for (int kt = 0; kt < 8; ++kt) {
            f32x4 s = {};
            #pragma unroll
            for (int ks = 0; ks < 2; ++ks) {
                int byte = ((kt * 16 + fr) * 128 + ks * 64 + kg * 16) ^ swz;
                bf16x8 kf = *reinterpret_cast<const bf16x8*>((const char*)Ks[cur] + byte);
                s = __builtin_amdgcn_mfma_f32_16x16x32_bf16(kf, qf[ks], s, 0, 0, 0);
            }
            st[kt] = s;
        }

        float sv[8][4];
        float mloc = -3.0e38f;
        #pragma unroll
        for (int kt = 0; kt < 8; ++kt) {
            unsigned long long vm = (kt < 4) ? vm0 : vm1;
            #pragma unroll
            for (int j = 0; j < 4; ++j) {
                int kl = kt * 16 + kg * 4 + j;
                float s = st[kt][j] * 0.125f;
                bool ok = (vm >> (kl & 63)) & 1ull;
                if (causal && (kk0 + kl > qrow)) ok = false;
                s = ok ? s : -1e9f;
                sv[kt][j] = s;
                mloc = fmaxf(mloc, s);
            }
        }
        mloc = fmaxf(mloc, __shfl_xor(mloc, 16));
        mloc = fmaxf(mloc, __shfl_xor(mloc, 32));
        float m_new = fmaxf(m_run, mloc);
        float scale = __expf(m_run - m_new);
        float ls = 0.f;
        #pragma unroll
        for (int kt = 0; kt < 8; ++kt)
            #pragma unroll
            for (int j = 0; j < 4; ++j) {
                float p = __expf(sv[kt][j] - m_new);
                sv[kt][j] = p;
                ls += p;
            }
        ls += __shfl_xor(ls, 16);
        ls += __shfl_xor(ls, 32);
        l_run = l_run * scale + ls;
        m_run = m_new;

        #pragma unroll
        for (int kt = 0; kt < 8; ++kt)
            #pragma unroll
            for (int c = 0; c < 2; ++c) {
                union { __bf16 hh[2]; unsigned u; } pk;
                pk.hh[0] = (__bf16)sv[kt][2 * c];
                pk.hh[1] = (__bf16)sv[kt][2 * c + 1];
                int byte = (fr * 256 + kt * 32 + kg * 8 + c * 4) ^ swz;
                *reinterpret_cast<unsigned*>((char*)pw + byte) = pk.u;
            }

        {
            int qb4 = kg * 4;
            float s0 = __shfl(scale, qb4 + 0), s1 = __shfl(scale, qb4 + 1);
            float s2 = __shfl(scale, qb4 + 2), s3 = __shfl(scale, qb4 + 3);
            #pragma unroll
            for (int nf = 0; nf < 4; ++nf) {
                po[nf][0] *= s0; po[nf][1] *= s1;
                po[nf][2] *= s2; po[nf][3] *= s3;
            }
        }

        #pragma unroll
        for (int ks2 = 0; ks2 < 4; ++ks2) {
            int pbyte = (fr * 256 + ks2 * 64 + kg * 16) ^ swz;
            bf16x8 pa = *reinterpret_cast<const bf16x8*>((const char*)pw + pbyte);
            #pragma unroll
            for (int nf = 0; nf < 4; ++nf) {
                int vbyte = ((nf * 16 + fr) * 256 + ks2 * 64 + kg * 16) ^ swz;
                bf16x8 vf = *reinterpret_cast<const bf16x8*>((const char*)Vs[cur] + vbyte);
                po[nf] = __builtin_amdgcn_mfma_f32_16x16x32_bf16(pa, vf, po[nf], 0, 0, 0);
            }
        }
        __syncthreads();
    }

    {
        int qb4 = kg * 4;
        float r0 = 1.0f / __shfl(l_run, qb4 + 0);
        float r1 = 1.0f / __shfl(l_run, qb4 + 1);
        float r2 = 1.0f / __shfl(l_run, qb4 + 2);
        float r3 = 1.0f / __shfl(l_run, qb4 + 3);
        #pragma unroll
        for (int nf = 0; nf < 4; ++nf) {
            size_t base = (size_t)(b * 512 + q0 + w * 16 + qb4) * 512 + h * 64 + nf * 16 + fr;
            Ob[base]           = (__bf16)(po[nf][0] * r0);
            Ob[base + 512]     = (__bf16)(po[nf][1] * r1);
            Ob[base + 1024]    = (__bf16)(po[nf][2] * r2);
            Ob[base + 1536]    = (__bf16)(po[nf][3] * r3);
        }
    }
}

// ---------------------------------------------------------------- residual + LN, bf16 stream
__global__ __launch_bounds__(256) void add_ln_b_k(__bf16* __restrict__ xb,
                                                  const __bf16* __restrict__ ab,
                                                  const float* __restrict__ g,
                                                  const float* __restrict__ bb)
{
    const int w = threadIdx.x >> 6, lane = threadIdx.x & 63;
    const int row = blockIdx.x * 4 + w;
    const size_t base = (size_t)row * Dm + lane * 8;
    bf16x8 xv = *reinterpret_cast<const bf16x8*>(&xb[base]);
    bf16x8 av = *reinterpret_cast<const bf16x8*>(&ab[base]);
    float v[8];
    float s = 0.f, s2 = 0.f;
    #pragma unroll
    for (int j = 0; j < 8; ++j) {
        v[j] = (float)xv[j] + (float)av[j];
        s += v[j];
        s2 += v[j] * v[j];
    }
    #pragma unroll
    for (int o = 1; o < 64; o <<= 1) {
        s  += __shfl_xor(s, o);
        s2 += __shfl_xor(s2, o);
    }
    float mean = s * (1.0f / 512.0f);
    float var  = s2 * (1.0f / 512.0f) - mean * mean;
    float rstd = rsqrtf(var + 1e-5f);
    float4 g0 = *reinterpret_cast<const float4*>(&g[lane * 8]);
    float4 g1 = *reinterpret_cast<const float4*>(&g[lane * 8 + 4]);
    float4 b0 = *reinterpret_cast<const float4*>(&bb[lane * 8]);
    float4 b1 = *reinterpret_cast<const float4*>(&bb[lane * 8 + 4]);
    float gv[8] = {g0.x, g0.y, g0.z, g0.w, g1.x, g1.y, g1.z, g1.w};
    float bv[8] = {b0.x, b0.y, b0.z, b0.w, b1.x, b1.y, b1.z, b1.w};
    bf16x8 yv;
    #pragma unroll
    for (int j = 0; j < 8; ++j)
        yv[j] = (__bf16)((v[j] - mean) * rstd * gv[j] + bv[j]);
    *reinterpret_cast<bf16x8*>(&xb[base]) = yv;
}

// ---------------------------------------------------------------- launch
extern "C" void kernel_launch(void* const* d_in, const int* in_sizes, int n_in,
                              void* d_out, int out_size, void* d_ws, size_t ws_size,
                              hipStream_t stream)
{
    const int*   src        = (const int*)  d_in[0];
    const int*   tgt        = (const int*)  d_in[1];
    const float* src_emb    = (const float*)d_in[2];
    const float* tgt_emb    = (const float*)d_in[3];
    const float* enc_attn_w = (const float*)d_in[4];
    const float* enc_attn_b = (const float*)d_in[5];
    const float* enc_ffn_w1 = (const float*)d_in[6];
    const float* enc_ffn_b1 = (const float*)d_in[7];
    const float* enc_ffn_w2 = (const float*)d_in[8];
    const float* enc_ffn_b2 = (const float*)d_in[9];
    const float* enc_ln_g   = (const float*)d_in[10];
    const float* enc_ln_b   = (const float*)d_in[11];
    const float* dec_self_w = (const float*)d_in[12];
    const float* dec_self_b = (const float*)d_in[13];
    const float* dec_cross_w= (const float*)d_in[14];
    const float* dec_cross_b= (const float*)d_in[15];
    const float* dec_ffn_w1 = (const float*)d_in[16];
    const float* dec_ffn_b1 = (const float*)d_in[17];
    const float* dec_ffn_w2 = (const float*)d_in[18];
    const float* dec_ffn_b2 = (const float*)d_in[19];
    const float* dec_ln_g   = (const float*)d_in[20];
    const float* dec_ln_b   = (const float*)d_in[21];
    const float* out_w      = (const float*)d_in[22];
    const float* out_b      = (const float*)d_in[23];

    const size_t NROW = NROWC;                    // 2,097,152
    const size_t NH1  = (size_t)NTOK * DFFv;      // 8,388,608

    __bf16* xeb  = (__bf16*)d_ws;         // bf16 encoder stream
    __bf16* xdb  = xeb + NROW;            // bf16 decoder stream
    __bf16* t0b  = xdb + NROW;            // bf16 sublayer output (pre-LN)
    __bf16* qbb  = t0b + NROW;
    __bf16* kbb  = qbb + NROW;
    __bf16* vbT  = kbb + NROW;            // [(b*8+h)*64+f][512]
    __bf16* ctxb = vbT + NROW;
    __bf16* h1b  = ctxb + NROW;           // [4096,2048] bf16
    __bf16* kbb6 = h1b + NH1;             // 6 layers cross-K
    __bf16* vbT6 = kbb6 + 6 * NROW;       // 6 layers cross-V (transposed)

    const size_t WSZ  = (size_t)Dm * Dm;          // 262144
    const size_t FSZ  = (size_t)Dm * DFFv;        // 1048576
    __bf16* w_enc_attn = vbT6 + 6 * NROW;
    __bf16* w_enc_f1   = w_enc_attn + 24 * WSZ;
    __bf16* w_enc_f2   = w_enc_f1 + 6 * FSZ;
    __bf16* w_dec_self = w_enc_f2 + 6 * FSZ;
    __bf16* w_dec_cross= w_dec_self + 24 * WSZ;
    __bf16* w_dec_f1   = w_dec_cross + 24 * WSZ;
    __bf16* w_dec_f2   = w_dec_f1 + 6 * FSZ;
    __bf16* w_out      = w_dec_f2 + 6 * FSZ;      // 512*32000

    // ---- weight transpose+convert (attn merged z=72; FFN pairs merged z=12)
    wtr_attn_k<<<dim3(Dm / 32, Dm / 32, 72), 256, 0, stream>>>(
        enc_attn_w, dec_self_w, dec_cross_w, w_enc_attn, w_dec_self, w_dec_cross);
    wtr2_k<<<dim3(DFFv / 32, Dm / 32, 12), 256, 0, stream>>>(
        enc_ffn_w1, dec_ffn_w1, w_enc_f1, w_dec_f1, Dm, DFFv);
    wtr2_k<<<dim3(Dm / 32, DFFv / 32, 12), 256, 0, stream>>>(
        enc_ffn_w2, dec_ffn_w2, w_enc_f2, w_dec_f2, DFFv, Dm);
    wtr_k<<<dim3(Vv / 32, Dm / 32, 1), 256, 0, stream>>>(out_w, w_out, Dm, Vv);

    auto gqkv = [&](const __bf16* A, const __bf16* Wt, const float* bias) {
        gemm_mfma_k<64, 128, 0, 2><<<dim3(1536 / 128, NTOK / 64), 256, 0, stream>>>(
            A, Wt, bias, qbb, kbb, vbT, NTOK, 1536, Dm);
    };
    auto g64b = [&](const __bf16* A, const __bf16* Wt, const float* bias, __bf16* C, int K) {
        gemm_mfma_k<64, 64, 0, 1><<<dim3(Dm / 64, NTOK / 64), 256, 0, stream>>>(
            A, Wt, bias, C, nullptr, nullptr, NTOK, Dm, K);
    };
    auto attn = [&](const __bf16* Q, const __bf16* K, const __bf16* Vt, __bf16* O,
                    const int* kt, int causal) {
        attn_mfma_k<<<dim3(Ss / 64, Hh, Bb), 256, 0, stream>>>(Q, K, Vt, O, kt, causal);
    };
    auto lnorm = [&](__bf16* xb, const __bf16* ab, const float* g, const float* b) {
        add_ln_b_k<<<NTOK / 4, 256, 0, stream>>>(xb, ab, g, b);
    };

    // embeddings + PE (both streams, one launch)
    embed_pe_k<<<dim3(NTOK, 2), 256, 0, stream>>>(src, tgt, src_emb, tgt_emb, xeb, xdb);

    // ---------------- encoder
    for (int i = 0; i < Ll; ++i) {
        const __bf16* W = w_enc_attn + (size_t)i * 4 * WSZ;
        const float* Bv = enc_attn_b + (size_t)i * 4 * Dm;
        gqkv(xeb, W, Bv);                               // q,k,v (+V transposed)
        attn(qbb, kbb, vbT, ctxb, src, 0);
        g64b(ctxb, W + 3 * WSZ, Bv + 3 * Dm, t0b, Dm);
        lnorm(xeb, t0b, enc_ln_g + i * 2 * Dm, enc_ln_b + i * 2 * Dm);
        gemm_mfma_k<128, 128, 1, 1><<<dim3(DFFv / 128, NTOK / 128), 256, 0, stream>>>(
            xeb, w_enc_f1 + (size_t)i * FSZ, enc_ffn_b1 + i * DFFv, h1b, nullptr, nullptr,
            NTOK, DFFv, Dm);
        g64b(h1b, w_enc_f2 + (size_t)i * FSZ, enc_ffn_b2 + i * Dm, t0b, DFFv);
        lnorm(xeb, t0b, enc_ln_g + i * 2 * Dm + Dm, enc_ln_b + i * 2 * Dm + Dm);
    }

    // ---------------- merged cross-KV for all 6 decoder layers (from memory xeb)
    gemm_mfma_k<64, 128, 0, 4><<<dim3(6144 / 128, NTOK / 64), 256, 0, stream>>>(
        xeb, w_dec_cross, dec_cross_b, nullptr, kbb6, vbT6, NTOK, 6144, Dm);

    // ---------------- decoder
    for (int i = 0; i < Ll; ++i) {
        const __bf16* Wsf = w_dec_self + (size_t)i * 4 * WSZ;
        const float* Bsf = dec_self_b + (size_t)i * 4 * Dm;
        gqkv(xdb, Wsf, Bsf);
        attn(qbb, kbb, vbT, ctxb, tgt, 1);                   // causal + tgt pad
        g64b(ctxb, Wsf + 3 * WSZ, Bsf + 3 * Dm, t0b, Dm);
        lnorm(xdb, t0b, dec_ln_g + i * 3 * Dm, dec_ln_b + i * 3 * Dm);

        const __bf16* Wc = w_dec_cross + (size_t)i * 4 * WSZ;
        const float* Bc = dec_cross_b + (size_t)i * 4 * Dm;
        g64b(xdb, Wc + 0 * WSZ, Bc + 0 * Dm, qbb, Dm);       // Q from post-LN decoder
        attn(qbb, kbb6 + (size_t)i * NROW, vbT6 + (size_t)i * NROW, ctxb, src, 0);
        g64b(ctxb, Wc + 3 * WSZ, Bc + 3 * Dm, t0b, Dm);
        lnorm(xdb, t0b, dec_ln_g + i * 3 * Dm + Dm, dec_ln_b + i * 3 * Dm + Dm);

        gemm_mfma_k<128, 128, 1, 1><<<dim3(DFFv / 128, NTOK / 128), 256, 0, stream>>>(
            xdb, w_dec_f1 + (size_t)i * FSZ, dec_ffn_b1 + i * DFFv, h1b, nullptr, nullptr,
            NTOK, DFFv, Dm);
        g64b(h1b, w_dec_f2 + (size_t)i * FSZ, dec_ffn_b2 + i * Dm, t0b, DFFv);
        lnorm(xdb, t0b, dec_ln_g + i * 3 * Dm + 2 * Dm, dec_ln_b + i * 3 * Dm + 2 * Dm);
    }

    // ---------------- final vocab projection -> d_out [8,512,32000] f32
    gemm256_k<<<2000, 512, 0, stream>>>(xdb, w_out, out_b, (float*)d_out, NTOK, Vv, Dm);
}